// Round 6
// baseline (1692.688 us; speedup 1.0000x reference)
//
#include <hip/hip_runtime.h>
#include <hip/hip_fp16.h>

#define NP 200000
#define NA 100000
#define NE 1200000
#define PROBE_R 8   // in-kernel idempotent repeats of each spmm pass (probe round)

// ---------------- CSR build ----------------

__global__ __launch_bounds__(256) void hist_k(const int* __restrict__ row, int* __restrict__ cnt, int n) {
    int i = blockIdx.x * blockDim.x + threadIdx.x;
    int stride = gridDim.x * blockDim.x;
    for (; i < n; i += stride) atomicAdd(&cnt[row[i]], 1);
}

// exclusive scan, 1024 elements/block (256 thr x 4), partial per block + block sums
__global__ __launch_bounds__(256) void scan1_k(const int* __restrict__ in, int* __restrict__ out,
                                               int* __restrict__ bsums, int n) {
    __shared__ int lds[256];
    int t = threadIdx.x;
    int base = blockIdx.x * 1024 + t * 4;
    int v0 = (base + 0 < n) ? in[base + 0] : 0;
    int v1 = (base + 1 < n) ? in[base + 1] : 0;
    int v2 = (base + 2 < n) ? in[base + 2] : 0;
    int v3 = (base + 3 < n) ? in[base + 3] : 0;
    lds[t] = v0 + v1 + v2 + v3;
    __syncthreads();
    for (int off = 1; off < 256; off <<= 1) {
        int x = (t >= off) ? lds[t - off] : 0;
        __syncthreads();
        lds[t] += x;
        __syncthreads();
    }
    if (t == 255) bsums[blockIdx.x] = lds[255];
    int run = (t == 0) ? 0 : lds[t - 1];
    if (base + 0 < n) out[base + 0] = run; run += v0;
    if (base + 1 < n) out[base + 1] = run; run += v1;
    if (base + 2 < n) out[base + 2] = run; run += v2;
    if (base + 3 < n) out[base + 3] = run;
}

__global__ void scan2_k(int* bsums, int nb) {  // nb <= 256, single block
    __shared__ int lds[256];
    int t = threadIdx.x;
    int v = (t < nb) ? bsums[t] : 0;
    lds[t] = v;
    __syncthreads();
    for (int off = 1; off < 256; off <<= 1) {
        int x = (t >= off) ? lds[t - off] : 0;
        __syncthreads();
        lds[t] += x;
        __syncthreads();
    }
    if (t < nb) bsums[t] = (t == 0) ? 0 : lds[t - 1];
}

__global__ __launch_bounds__(256) void scan3_k(int* __restrict__ out, const int* __restrict__ bsums, int n) {
    int add = bsums[blockIdx.x];
    int base = blockIdx.x * 1024 + threadIdx.x * 4;
#pragma unroll
    for (int j = 0; j < 4; j++)
        if (base + j < n) out[base + j] += add;
}

__global__ __launch_bounds__(256) void scatter_k(const int* __restrict__ row, const int* __restrict__ col,
                                                 const float* __restrict__ val, const int* __restrict__ off,
                                                 int* __restrict__ cursor, int2* __restrict__ csr, int n) {
    int i = blockIdx.x * blockDim.x + threadIdx.x;
    int stride = gridDim.x * blockDim.x;
    for (; i < n; i += stride) {
        int r = row[i];
        int pos = off[r] + atomicAdd(&cursor[r], 1);
        csr[pos] = make_int2(col[i], __float_as_int(val[i]));
    }
}

// ---------------- SpMM gather, fp16 z-table ----------------
// 8 lanes per output row; each lane covers 8 dims (uint4 = 8 halves = 16B,
// 8 lanes x 16B = 128B coalesced per gathered z-row). fp32 accumulate.
// PROBE: template R repeats the (idempotent) row computation R times so the
// dispatch exceeds the harness fills and shows in the counter top-5.

__device__ __forceinline__ void fma_h8(float acc[8], float v, uint4 r) {
    __half2 h0 = *(__half2*)&r.x;
    __half2 h1 = *(__half2*)&r.y;
    __half2 h2 = *(__half2*)&r.z;
    __half2 h3 = *(__half2*)&r.w;
    float2 f0 = __half22float2(h0);
    float2 f1 = __half22float2(h1);
    float2 f2 = __half22float2(h2);
    float2 f3 = __half22float2(h3);
    acc[0] = fmaf(v, f0.x, acc[0]);
    acc[1] = fmaf(v, f0.y, acc[1]);
    acc[2] = fmaf(v, f1.x, acc[2]);
    acc[3] = fmaf(v, f1.y, acc[3]);
    acc[4] = fmaf(v, f2.x, acc[4]);
    acc[5] = fmaf(v, f2.y, acc[5]);
    acc[6] = fmaf(v, f3.x, acc[6]);
    acc[7] = fmaf(v, f3.y, acc[7]);
}

__device__ __forceinline__ void store_h8(uint4* out16, int g, int l, const float acc[8]) {
    __half2 p0 = __floats2half2_rn(acc[0], acc[1]);
    __half2 p1 = __floats2half2_rn(acc[2], acc[3]);
    __half2 p2 = __floats2half2_rn(acc[4], acc[5]);
    __half2 p3 = __floats2half2_rn(acc[6], acc[7]);
    uint4 o;
    o.x = *(unsigned*)&p0;
    o.y = *(unsigned*)&p1;
    o.z = *(unsigned*)&p2;
    o.w = *(unsigned*)&p3;
    out16[(size_t)g * 8 + l] = o;
}

__device__ __forceinline__ void store_f8(float4* out32, int g, int l, const float acc[8]) {
    out32[(size_t)g * 16 + l * 2 + 0] = make_float4(acc[0], acc[1], acc[2], acc[3]);
    out32[(size_t)g * 16 + l * 2 + 1] = make_float4(acc[4], acc[5], acc[6], acc[7]);
}

template <int R>
__global__ __launch_bounds__(256) void spmm_k(const int2* __restrict__ csr, const int* __restrict__ off,
                                              const int* __restrict__ cnt, const uint4* __restrict__ z,
                                              float4* __restrict__ out32, uint4* __restrict__ out16,
                                              int nrows) {
    int g = blockIdx.x * 32 + (threadIdx.x >> 3);
    int l = threadIdx.x & 7;
    if (g >= nrows) return;
    int start = off[g], deg = cnt[g];

    for (int rep = 0; rep < R; ++rep) {
        float acc[8];
#pragma unroll
        for (int i = 0; i < 8; i++) acc[i] = 0.f;

        if (deg > 0) {
            int2 e[8];
#pragma unroll
            for (int k = 0; k < 8; k++) e[k] = csr[start + min(k, deg - 1)];
            for (int j = 0; j < deg; j += 8) {
                uint4 r[8];
#pragma unroll
                for (int k = 0; k < 8; k++) r[k] = z[e[k].x * 8 + l];
                float v[8];
#pragma unroll
                for (int k = 0; k < 8; k++) v[k] = (j + k < deg) ? __int_as_float(e[k].y) : 0.f;
                int2 en[8];
                bool more = (j + 8) < deg;
                if (more) {
#pragma unroll
                    for (int k = 0; k < 8; k++) en[k] = csr[start + min(j + 8 + k, deg - 1)];
                }
#pragma unroll
                for (int k = 0; k < 8; k++) fma_h8(acc, v[k], r[k]);
                if (more) {
#pragma unroll
                    for (int k = 0; k < 8; k++) e[k] = en[k];
                }
            }
        }
        if (out32) store_f8(out32, g, l, acc);
        if (out16) store_h8(out16, g, l, acc);
        asm volatile("" ::: "memory");  // prevent cross-rep CSE/hoisting
    }
}

// Fused dual-operand SpMM: same CSR, same gather indices, two dense tables.
template <int R>
__global__ __launch_bounds__(256) void spmm2_k(const int2* __restrict__ csr, const int* __restrict__ off,
                                               const int* __restrict__ cnt,
                                               const uint4* __restrict__ zA, const uint4* __restrict__ zB,
                                               float4* __restrict__ outA32, uint4* __restrict__ outA16,
                                               float4* __restrict__ outB32, uint4* __restrict__ outB16,
                                               int nrows) {
    int g = blockIdx.x * 32 + (threadIdx.x >> 3);
    int l = threadIdx.x & 7;
    if (g >= nrows) return;
    int start = off[g], deg = cnt[g];

    for (int rep = 0; rep < R; ++rep) {
        float accA[8], accB[8];
#pragma unroll
        for (int i = 0; i < 8; i++) { accA[i] = 0.f; accB[i] = 0.f; }

        if (deg > 0) {
            int2 e[8];
#pragma unroll
            for (int k = 0; k < 8; k++) e[k] = csr[start + min(k, deg - 1)];
            for (int j = 0; j < deg; j += 8) {
                uint4 rA[8], rB[8];
#pragma unroll
                for (int k = 0; k < 8; k++) {
                    int idx = e[k].x * 8 + l;
                    rA[k] = zA[idx];
                    rB[k] = zB[idx];
                }
                float v[8];
#pragma unroll
                for (int k = 0; k < 8; k++) v[k] = (j + k < deg) ? __int_as_float(e[k].y) : 0.f;
                int2 en[8];
                bool more = (j + 8) < deg;
                if (more) {
#pragma unroll
                    for (int k = 0; k < 8; k++) en[k] = csr[start + min(j + 8 + k, deg - 1)];
                }
#pragma unroll
                for (int k = 0; k < 8; k++) {
                    fma_h8(accA, v[k], rA[k]);
                    fma_h8(accB, v[k], rB[k]);
                }
                if (more) {
#pragma unroll
                    for (int k = 0; k < 8; k++) e[k] = en[k];
                }
            }
        }
        if (outA32) store_f8(outA32, g, l, accA);
        if (outA16) store_h8(outA16, g, l, accA);
        if (outB32) store_f8(outB32, g, l, accB);
        if (outB16) store_h8(outB16, g, l, accB);
        asm volatile("" ::: "memory");  // prevent cross-rep CSE/hoisting
    }
}

// ---------------- dense projection: z16 = fp16(x @ W), D=64 ----------------

template <int K>
__global__ __launch_bounds__(256) void gemm64_k(const float* __restrict__ x, const float* __restrict__ w,
                                                __half* __restrict__ z16, int nrows) {
    __shared__ float xs[32][256];  // [kk][row_local]
    __shared__ float wsh[32][64];  // [kk][col]
    int t = threadIdx.x;
    int tx = t & 7;    // col group: cols tx*8 .. tx*8+7
    int ty = t >> 3;   // row group: rows ty*8 .. ty*8+7
    int r0 = blockIdx.x * 256;

    float acc[8][8];
#pragma unroll
    for (int i = 0; i < 8; i++)
#pragma unroll
        for (int j = 0; j < 8; j++) acc[i][j] = 0.f;

    for (int k0 = 0; k0 < K; k0 += 32) {
        __syncthreads();  // previous tile fully consumed
        {
            int row = r0 + t;
            float4 f[8];
            if (row < nrows) {
                const float* xp = x + (size_t)row * K + k0;
#pragma unroll
                for (int q = 0; q < 8; q++) f[q] = *(const float4*)&xp[q * 4];
            } else {
#pragma unroll
                for (int q = 0; q < 8; q++) f[q] = make_float4(0.f, 0.f, 0.f, 0.f);
            }
#pragma unroll
            for (int q = 0; q < 8; q++) {
                xs[q * 4 + 0][t] = f[q].x;
                xs[q * 4 + 1][t] = f[q].y;
                xs[q * 4 + 2][t] = f[q].z;
                xs[q * 4 + 3][t] = f[q].w;
            }
            const float* wp = w + (size_t)k0 * 64;
            float* wflat = &wsh[0][0];
            *(float4*)&wflat[t * 8 + 0] = *(const float4*)&wp[t * 8 + 0];
            *(float4*)&wflat[t * 8 + 4] = *(const float4*)&wp[t * 8 + 4];
        }
        __syncthreads();
#pragma unroll 8
        for (int kk = 0; kk < 32; kk++) {
            float a[8], b[8];
            *(float4*)&a[0] = *(float4*)&xs[kk][ty * 8 + 0];
            *(float4*)&a[4] = *(float4*)&xs[kk][ty * 8 + 4];
            *(float4*)&b[0] = *(float4*)&wsh[kk][tx * 8 + 0];
            *(float4*)&b[4] = *(float4*)&wsh[kk][tx * 8 + 4];
#pragma unroll
            for (int i = 0; i < 8; i++)
#pragma unroll
                for (int j = 0; j < 8; j++) acc[i][j] = fmaf(a[i], b[j], acc[i][j]);
        }
    }

    int row0 = r0 + ty * 8;
    if (row0 < nrows) {
#pragma unroll
        for (int i = 0; i < 8; i++) {
            __half2 p0 = __floats2half2_rn(acc[i][0], acc[i][1]);
            __half2 p1 = __floats2half2_rn(acc[i][2], acc[i][3]);
            __half2 p2 = __floats2half2_rn(acc[i][4], acc[i][5]);
            __half2 p3 = __floats2half2_rn(acc[i][6], acc[i][7]);
            uint4 o;
            o.x = *(unsigned*)&p0;
            o.y = *(unsigned*)&p1;
            o.z = *(unsigned*)&p2;
            o.w = *(unsigned*)&p3;
            *(uint4*)&z16[(size_t)(row0 + i) * 64 + tx * 8] = o;
        }
    }
}

// ---------------- launch ----------------

extern "C" void kernel_launch(void* const* d_in, const int* in_sizes, int n_in,
                              void* d_out, int out_size, void* d_ws, size_t ws_size,
                              hipStream_t stream) {
    const float* x_paper  = (const float*)d_in[0];
    const float* x_author = (const float*)d_in[1];
    const float* W_paper  = (const float*)d_in[2];
    const float* W_author = (const float*)d_in[3];
    const int*   pa_row   = (const int*)d_in[4];
    const int*   pa_col   = (const int*)d_in[5];
    const float* pa_val   = (const float*)d_in[6];
    const int*   ap_row   = (const int*)d_in[7];
    const int*   ap_col   = (const int*)d_in[8];
    const float* ap_val   = (const float*)d_in[9];

    char* ws = (char*)d_ws;
    size_t o = 0;
    auto alloc = [&](size_t bytes) -> char* {
        char* p = ws + o;
        o += (bytes + 255) & ~(size_t)255;
        return p;
    };
    __half* zp16  = (__half*)alloc((size_t)NP * 64 * 2);  // zp, later reused as g
    __half* za16  = (__half*)alloc((size_t)NA * 64 * 2);
    __half* h16   = (__half*)alloc((size_t)NA * 64 * 2);  // h, later h2
    __half* pap16 = (__half*)alloc((size_t)NP * 64 * 2);
    int2*  csr_pa = (int2*)alloc((size_t)NE * 8);
    int2*  csr_ap = (int2*)alloc((size_t)NE * 8);
    int* cnt_pa = (int*)alloc(NA * 4);
    int* off_pa = (int*)alloc(NA * 4);
    int* cnt_ap = (int*)alloc(NP * 4);
    int* off_ap = (int*)alloc(NP * 4);
    int* cursor = (int*)alloc(NP * 4);
    int* bsums  = (int*)alloc(1024 * 4);

    float* out_pap   = (float*)d_out;
    float* out_papap = out_pap + (size_t)NP * 64;
    float* out_apa   = out_papap + (size_t)NP * 64;

    const int nb_a = (NA + 1023) / 1024;  // 98
    const int nb_p = (NP + 1023) / 1024;  // 196

    // CSR build: pa (rows = authors), ap (rows = papers)
    hipMemsetAsync(cnt_pa, 0, NA * 4, stream);
    hipMemsetAsync(cnt_ap, 0, NP * 4, stream);
    hist_k<<<1024, 256, 0, stream>>>(pa_row, cnt_pa, NE);
    hist_k<<<1024, 256, 0, stream>>>(ap_row, cnt_ap, NE);

    scan1_k<<<nb_a, 256, 0, stream>>>(cnt_pa, off_pa, bsums, NA);
    scan2_k<<<1, 256, 0, stream>>>(bsums, nb_a);
    scan3_k<<<nb_a, 256, 0, stream>>>(off_pa, bsums, NA);
    hipMemsetAsync(cursor, 0, NA * 4, stream);
    scatter_k<<<1024, 256, 0, stream>>>(pa_row, pa_col, pa_val, off_pa, cursor, csr_pa, NE);

    scan1_k<<<nb_p, 256, 0, stream>>>(cnt_ap, off_ap, bsums, NP);
    scan2_k<<<1, 256, 0, stream>>>(bsums, nb_p);
    scan3_k<<<nb_p, 256, 0, stream>>>(off_ap, bsums, NP);
    hipMemsetAsync(cursor, 0, NP * 4, stream);
    scatter_k<<<1024, 256, 0, stream>>>(ap_row, ap_col, ap_val, off_ap, cursor, csr_ap, NE);

    // projections (register-tiled GEMM, fp16 output)
    gemm64_k<256><<<(NP + 255) / 256, 256, 0, stream>>>(x_paper, W_paper, zp16, NP);
    gemm64_k<128><<<(NA + 255) / 256, 256, 0, stream>>>(x_author, W_author, za16, NA);

    // pass 1: h = pa@zp (fp16)           [PROBE_R in-kernel repeats, idempotent]
    spmm_k<PROBE_R><<<NA / 32, 256, 0, stream>>>(csr_pa, off_pa, cnt_pa, (const uint4*)zp16,
                                                 nullptr, (uint4*)h16, NA);
    // pass 2 (fused over csr_ap): pap = ap@h (fp32 out + fp16) ; g = ap@za (fp16, reuse zp16)
    spmm2_k<PROBE_R><<<NP / 32, 256, 0, stream>>>(csr_ap, off_ap, cnt_ap,
                                                  (const uint4*)h16, (const uint4*)za16,
                                                  (float4*)out_pap, (uint4*)pap16,
                                                  nullptr, (uint4*)zp16, NP);
    // pass 3 (fused over csr_pa): h2 = pa@pap (fp16, reuse h16) ; apa = pa@g (fp32 out)
    spmm2_k<PROBE_R><<<NA / 32, 256, 0, stream>>>(csr_pa, off_pa, cnt_pa,
                                                  (const uint4*)pap16, (const uint4*)zp16,
                                                  nullptr, (uint4*)h16,
                                                  (float4*)out_apa, nullptr, NA);
    // pass 4: papap = ap@h2 (fp32 out)
    spmm_k<PROBE_R><<<NP / 32, 256, 0, stream>>>(csr_ap, off_ap, cnt_ap, (const uint4*)h16,
                                                 (float4*)out_papap, nullptr, NP);
}

// Round 7
// 784.280 us; speedup vs baseline: 2.1583x; 2.1583x over previous
//
#include <hip/hip_runtime.h>
#include <hip/hip_fp16.h>

#define NP 200000
#define NA 100000
#define NE 1200000
#define NTOT (NA + NP)          // concatenated row-count space: [authors | papers]
#define NBP_GEMM 3125           // NP/64
#define NBA_GEMM 1563           // ceil(NA/64)

typedef _Float16 half8 __attribute__((ext_vector_type(8)));
typedef float f32x4 __attribute__((ext_vector_type(4)));

// ---------------- CSR build (fused: both matrices in one pass) ----------------

__global__ __launch_bounds__(256) void hist2_k(const int* __restrict__ pa_row, const int* __restrict__ ap_row,
                                               int* __restrict__ cnt_all) {
    int i = blockIdx.x * blockDim.x + threadIdx.x;
    int stride = gridDim.x * blockDim.x;
    for (; i < 2 * NE; i += stride) {
        if (i < NE) atomicAdd(&cnt_all[pa_row[i]], 1);
        else        atomicAdd(&cnt_all[NA + ap_row[i - NE]], 1);
    }
}

// exclusive scan, 1024 elements/block (256 thr x 4), partial per block + block sums
__global__ __launch_bounds__(256) void scan1_k(const int* __restrict__ in, int* __restrict__ out,
                                               int* __restrict__ bsums, int n) {
    __shared__ int lds[256];
    int t = threadIdx.x;
    int base = blockIdx.x * 1024 + t * 4;
    int v0 = (base + 0 < n) ? in[base + 0] : 0;
    int v1 = (base + 1 < n) ? in[base + 1] : 0;
    int v2 = (base + 2 < n) ? in[base + 2] : 0;
    int v3 = (base + 3 < n) ? in[base + 3] : 0;
    lds[t] = v0 + v1 + v2 + v3;
    __syncthreads();
    for (int off = 1; off < 256; off <<= 1) {
        int x = (t >= off) ? lds[t - off] : 0;
        __syncthreads();
        lds[t] += x;
        __syncthreads();
    }
    if (t == 255) bsums[blockIdx.x] = lds[255];
    int run = (t == 0) ? 0 : lds[t - 1];
    if (base + 0 < n) out[base + 0] = run; run += v0;
    if (base + 1 < n) out[base + 1] = run; run += v1;
    if (base + 2 < n) out[base + 2] = run; run += v2;
    if (base + 3 < n) out[base + 3] = run;
}

__global__ void scan2_k(int* bsums, int nb) {  // nb <= 512, single block of 512
    __shared__ int lds[512];
    int t = threadIdx.x;
    int v = (t < nb) ? bsums[t] : 0;
    lds[t] = v;
    __syncthreads();
    for (int off = 1; off < 512; off <<= 1) {
        int x = (t >= off) ? lds[t - off] : 0;
        __syncthreads();
        lds[t] += x;
        __syncthreads();
    }
    if (t < nb) bsums[t] = lds[t] - v;  // exclusive
}

__global__ __launch_bounds__(256) void scan3_k(int* __restrict__ out, const int* __restrict__ bsums, int n) {
    int add = bsums[blockIdx.x];
    int base = blockIdx.x * 1024 + threadIdx.x * 4;
#pragma unroll
    for (int j = 0; j < 4; j++)
        if (base + j < n) out[base + j] += add;
}

// scatter both edge lists into one CSR buffer; ap region lands at [NE, 2NE) automatically
__global__ __launch_bounds__(256) void scatter2_k(const int* __restrict__ pa_row, const int* __restrict__ pa_col,
                                                  const float* __restrict__ pa_val,
                                                  const int* __restrict__ ap_row, const int* __restrict__ ap_col,
                                                  const float* __restrict__ ap_val,
                                                  const int* __restrict__ off_all, int* __restrict__ cursor,
                                                  int2* __restrict__ csr_all) {
    int i = blockIdx.x * blockDim.x + threadIdx.x;
    int stride = gridDim.x * blockDim.x;
    for (; i < 2 * NE; i += stride) {
        if (i < NE) {
            int r = pa_row[i];
            int pos = off_all[r] + atomicAdd(&cursor[r], 1);
            csr_all[pos] = make_int2(pa_col[i], __float_as_int(pa_val[i]));
        } else {
            int r = NA + ap_row[i - NE];
            int pos = off_all[r] + atomicAdd(&cursor[r], 1);
            csr_all[pos] = make_int2(ap_col[i - NE], __float_as_int(ap_val[i - NE]));
        }
    }
}

// ---------------- SpMM gather, fp16 z-table (unchanged from R5, probe removed) ----------------

__device__ __forceinline__ void fma_h8(float acc[8], float v, uint4 r) {
    __half2 h0 = *(__half2*)&r.x;
    __half2 h1 = *(__half2*)&r.y;
    __half2 h2 = *(__half2*)&r.z;
    __half2 h3 = *(__half2*)&r.w;
    float2 f0 = __half22float2(h0);
    float2 f1 = __half22float2(h1);
    float2 f2 = __half22float2(h2);
    float2 f3 = __half22float2(h3);
    acc[0] = fmaf(v, f0.x, acc[0]);
    acc[1] = fmaf(v, f0.y, acc[1]);
    acc[2] = fmaf(v, f1.x, acc[2]);
    acc[3] = fmaf(v, f1.y, acc[3]);
    acc[4] = fmaf(v, f2.x, acc[4]);
    acc[5] = fmaf(v, f2.y, acc[5]);
    acc[6] = fmaf(v, f3.x, acc[6]);
    acc[7] = fmaf(v, f3.y, acc[7]);
}

__device__ __forceinline__ void store_h8(uint4* out16, int g, int l, const float acc[8]) {
    __half2 p0 = __floats2half2_rn(acc[0], acc[1]);
    __half2 p1 = __floats2half2_rn(acc[2], acc[3]);
    __half2 p2 = __floats2half2_rn(acc[4], acc[5]);
    __half2 p3 = __floats2half2_rn(acc[6], acc[7]);
    uint4 o;
    o.x = *(unsigned*)&p0;
    o.y = *(unsigned*)&p1;
    o.z = *(unsigned*)&p2;
    o.w = *(unsigned*)&p3;
    out16[(size_t)g * 8 + l] = o;
}

__device__ __forceinline__ void store_f8(float4* out32, int g, int l, const float acc[8]) {
    out32[(size_t)g * 16 + l * 2 + 0] = make_float4(acc[0], acc[1], acc[2], acc[3]);
    out32[(size_t)g * 16 + l * 2 + 1] = make_float4(acc[4], acc[5], acc[6], acc[7]);
}

__global__ __launch_bounds__(256) void spmm_k(const int2* __restrict__ csr, const int* __restrict__ off,
                                              const int* __restrict__ cnt, const uint4* __restrict__ z,
                                              float4* __restrict__ out32, uint4* __restrict__ out16,
                                              int nrows) {
    int g = blockIdx.x * 32 + (threadIdx.x >> 3);
    int l = threadIdx.x & 7;
    if (g >= nrows) return;
    int start = off[g], deg = cnt[g];
    float acc[8];
#pragma unroll
    for (int i = 0; i < 8; i++) acc[i] = 0.f;

    if (deg > 0) {
        int2 e[8];
#pragma unroll
        for (int k = 0; k < 8; k++) e[k] = csr[start + min(k, deg - 1)];
        for (int j = 0; j < deg; j += 8) {
            uint4 r[8];
#pragma unroll
            for (int k = 0; k < 8; k++) r[k] = z[e[k].x * 8 + l];
            float v[8];
#pragma unroll
            for (int k = 0; k < 8; k++) v[k] = (j + k < deg) ? __int_as_float(e[k].y) : 0.f;
            int2 en[8];
            bool more = (j + 8) < deg;
            if (more) {
#pragma unroll
                for (int k = 0; k < 8; k++) en[k] = csr[start + min(j + 8 + k, deg - 1)];
            }
#pragma unroll
            for (int k = 0; k < 8; k++) fma_h8(acc, v[k], r[k]);
            if (more) {
#pragma unroll
                for (int k = 0; k < 8; k++) e[k] = en[k];
            }
        }
    }
    if (out32) store_f8(out32, g, l, acc);
    if (out16) store_h8(out16, g, l, acc);
}

__global__ __launch_bounds__(256) void spmm2_k(const int2* __restrict__ csr, const int* __restrict__ off,
                                               const int* __restrict__ cnt,
                                               const uint4* __restrict__ zA, const uint4* __restrict__ zB,
                                               float4* __restrict__ outA32, uint4* __restrict__ outA16,
                                               float4* __restrict__ outB32, uint4* __restrict__ outB16,
                                               int nrows) {
    int g = blockIdx.x * 32 + (threadIdx.x >> 3);
    int l = threadIdx.x & 7;
    if (g >= nrows) return;
    int start = off[g], deg = cnt[g];
    float accA[8], accB[8];
#pragma unroll
    for (int i = 0; i < 8; i++) { accA[i] = 0.f; accB[i] = 0.f; }

    if (deg > 0) {
        int2 e[8];
#pragma unroll
        for (int k = 0; k < 8; k++) e[k] = csr[start + min(k, deg - 1)];
        for (int j = 0; j < deg; j += 8) {
            uint4 rA[8], rB[8];
#pragma unroll
            for (int k = 0; k < 8; k++) {
                int idx = e[k].x * 8 + l;
                rA[k] = zA[idx];
                rB[k] = zB[idx];
            }
            float v[8];
#pragma unroll
            for (int k = 0; k < 8; k++) v[k] = (j + k < deg) ? __int_as_float(e[k].y) : 0.f;
            int2 en[8];
            bool more = (j + 8) < deg;
            if (more) {
#pragma unroll
                for (int k = 0; k < 8; k++) en[k] = csr[start + min(j + 8 + k, deg - 1)];
            }
#pragma unroll
            for (int k = 0; k < 8; k++) {
                fma_h8(accA, v[k], rA[k]);
                fma_h8(accB, v[k], rB[k]);
            }
            if (more) {
#pragma unroll
                for (int k = 0; k < 8; k++) e[k] = en[k];
            }
        }
    }
    if (outA32) store_f8(outA32, g, l, accA);
    if (outA16) store_h8(outA16, g, l, accA);
    if (outB32) store_f8(outB32, g, l, accB);
    if (outB16) store_h8(outB16, g, l, accB);
}

// ---------------- dense projection via fp16 MFMA ----------------
// W pre-transposed+converted to fp16: wt[64][K] row-major (wt[c][k] = W[k][c]).
// mfma_f32_16x16x32_f16 layouts (m89/m91/m92-verified conventions):
//   A: row = l&15, k = 8*(l>>4)+{0..7} (contiguous -> 16B vec load)
//   B: col = l&15, k = 8*(l>>4)+{0..7} (contiguous from wt row)
//   C/D: reg i -> row = 4*(l>>4)+i, col = l&15

__global__ __launch_bounds__(256) void wconv_k(const float* __restrict__ Wp, const float* __restrict__ Wa,
                                               __half* __restrict__ wtP, __half* __restrict__ wtA) {
    int i = blockIdx.x * 256 + threadIdx.x;
    int stride = gridDim.x * 256;
    for (int idx = i; idx < 64 * 256; idx += stride) {
        int c = idx >> 8, k = idx & 255;
        wtP[idx] = (__half)Wp[k * 64 + c];
    }
    for (int idx = i; idx < 64 * 128; idx += stride) {
        int c = idx >> 7, k = idx & 127;
        wtA[idx] = (__half)Wa[k * 64 + c];
    }
}

// one launch, both projections: blocks [0,NBP_GEMM) -> papers, rest -> authors.
// block = 256 thr = 4 waves; each wave computes 16 rows x 64 cols.
__global__ __launch_bounds__(256) void gemm_mfma_k(const float* __restrict__ xP, const float* __restrict__ xA,
                                                   const __half* __restrict__ wtP, const __half* __restrict__ wtA,
                                                   __half* __restrict__ zP, __half* __restrict__ zA) {
    int b = blockIdx.x;
    const float* x;
    const __half* wt;
    __half* z;
    int K, nrows, r0;
    if (b < NBP_GEMM) { x = xP; wt = wtP; z = zP; K = 256; nrows = NP; r0 = b * 64; }
    else              { x = xA; wt = wtA; z = zA; K = 128; nrows = NA; r0 = (b - NBP_GEMM) * 64; }

    int w = threadIdx.x >> 6;   // wave 0..3
    int l = threadIdx.x & 63;
    int arow = r0 + w * 16 + (l & 15);
    int kq = (l >> 4) * 8;

    f32x4 acc0 = {0.f, 0.f, 0.f, 0.f};
    f32x4 acc1 = {0.f, 0.f, 0.f, 0.f};
    f32x4 acc2 = {0.f, 0.f, 0.f, 0.f};
    f32x4 acc3 = {0.f, 0.f, 0.f, 0.f};

    for (int k0 = 0; k0 < K; k0 += 32) {
        half8 a;
        if (arow < nrows) {
            const float* xp = x + (size_t)arow * K + k0 + kq;
            float4 f0 = *(const float4*)xp;
            float4 f1 = *(const float4*)(xp + 4);
            a[0] = (_Float16)f0.x; a[1] = (_Float16)f0.y;
            a[2] = (_Float16)f0.z; a[3] = (_Float16)f0.w;
            a[4] = (_Float16)f1.x; a[5] = (_Float16)f1.y;
            a[6] = (_Float16)f1.z; a[7] = (_Float16)f1.w;
        } else {
#pragma unroll
            for (int j = 0; j < 8; j++) a[j] = (_Float16)0.f;
        }
        const __half* wbase = wt + (size_t)(l & 15) * K + k0 + kq;
        half8 b0 = *(const half8*)(wbase);                       // cols 0..15
        half8 b1 = *(const half8*)(wbase + (size_t)16 * K);      // cols 16..31
        half8 b2 = *(const half8*)(wbase + (size_t)32 * K);      // cols 32..47
        half8 b3 = *(const half8*)(wbase + (size_t)48 * K);      // cols 48..63
        acc0 = __builtin_amdgcn_mfma_f32_16x16x32_f16(a, b0, acc0, 0, 0, 0);
        acc1 = __builtin_amdgcn_mfma_f32_16x16x32_f16(a, b1, acc1, 0, 0, 0);
        acc2 = __builtin_amdgcn_mfma_f32_16x16x32_f16(a, b2, acc2, 0, 0, 0);
        acc3 = __builtin_amdgcn_mfma_f32_16x16x32_f16(a, b3, acc3, 0, 0, 0);
    }

    int orow0 = r0 + w * 16 + (l >> 4) * 4;
    int col = l & 15;
#pragma unroll
    for (int i = 0; i < 4; i++) {
        int r = orow0 + i;
        if (r < nrows) {
            __half* zr = z + (size_t)r * 64;
            zr[col +  0] = (__half)acc0[i];
            zr[col + 16] = (__half)acc1[i];
            zr[col + 32] = (__half)acc2[i];
            zr[col + 48] = (__half)acc3[i];
        }
    }
}

// ---------------- launch ----------------

extern "C" void kernel_launch(void* const* d_in, const int* in_sizes, int n_in,
                              void* d_out, int out_size, void* d_ws, size_t ws_size,
                              hipStream_t stream) {
    const float* x_paper  = (const float*)d_in[0];
    const float* x_author = (const float*)d_in[1];
    const float* W_paper  = (const float*)d_in[2];
    const float* W_author = (const float*)d_in[3];
    const int*   pa_row   = (const int*)d_in[4];
    const int*   pa_col   = (const int*)d_in[5];
    const float* pa_val   = (const float*)d_in[6];
    const int*   ap_row   = (const int*)d_in[7];
    const int*   ap_col   = (const int*)d_in[8];
    const float* ap_val   = (const float*)d_in[9];

    char* ws = (char*)d_ws;
    size_t o = 0;
    auto alloc = [&](size_t bytes) -> char* {
        char* p = ws + o;
        o += (bytes + 255) & ~(size_t)255;
        return p;
    };
    __half* zp16  = (__half*)alloc((size_t)NP * 64 * 2);  // zp, later reused as g
    __half* za16  = (__half*)alloc((size_t)NA * 64 * 2);
    __half* h16   = (__half*)alloc((size_t)NA * 64 * 2);  // h, later h2
    __half* pap16 = (__half*)alloc((size_t)NP * 64 * 2);
    int2*  csr_all = (int2*)alloc((size_t)2 * NE * 8);    // [pa | ap], ap at offset NE
    int* cnt_all = (int*)alloc(NTOT * 4);                 // [authors(pa rows) | papers(ap rows)]
    int* off_all = (int*)alloc(NTOT * 4);
    int* cursor  = (int*)alloc(NTOT * 4);
    int* bsums   = (int*)alloc(1024 * 4);
    __half* wtP  = (__half*)alloc(64 * 256 * 2);
    __half* wtA  = (__half*)alloc(64 * 128 * 2);

    float* out_pap   = (float*)d_out;
    float* out_papap = out_pap + (size_t)NP * 64;
    float* out_apa   = out_papap + (size_t)NP * 64;

    const int nb_tot = (NTOT + 1023) / 1024;  // 293

    // CSR build (fused)
    hipMemsetAsync(cnt_all, 0, NTOT * 4, stream);
    hist2_k<<<1024, 256, 0, stream>>>(pa_row, ap_row, cnt_all);
    scan1_k<<<nb_tot, 256, 0, stream>>>(cnt_all, off_all, bsums, NTOT);
    scan2_k<<<1, 512, 0, stream>>>(bsums, nb_tot);
    scan3_k<<<nb_tot, 256, 0, stream>>>(off_all, bsums, NTOT);
    hipMemsetAsync(cursor, 0, NTOT * 4, stream);
    scatter2_k<<<1024, 256, 0, stream>>>(pa_row, pa_col, pa_val, ap_row, ap_col, ap_val,
                                         off_all, cursor, csr_all);

    // projections (fp16 MFMA)
    wconv_k<<<64, 256, 0, stream>>>(W_paper, W_author, wtP, wtA);
    gemm_mfma_k<<<NBP_GEMM + NBA_GEMM, 256, 0, stream>>>(x_paper, x_author, wtP, wtA, zp16, za16);

    const int* off_pa = off_all;        // author rows
    const int* cnt_pa = cnt_all;
    const int* off_ap = off_all + NA;   // paper rows (absolute offsets into csr_all)
    const int* cnt_ap = cnt_all + NA;

    // pass 1: h = pa@zp (fp16)
    spmm_k<<<NA / 32, 256, 0, stream>>>(csr_all, off_pa, cnt_pa, (const uint4*)zp16,
                                        nullptr, (uint4*)h16, NA);
    // pass 2 (fused over ap): pap = ap@h (fp32 + fp16) ; g = ap@za (fp16, reuse zp16)
    spmm2_k<<<NP / 32, 256, 0, stream>>>(csr_all, off_ap, cnt_ap,
                                         (const uint4*)h16, (const uint4*)za16,
                                         (float4*)out_pap, (uint4*)pap16,
                                         nullptr, (uint4*)zp16, NP);
    // pass 3 (fused over pa): h2 = pa@pap (fp16, reuse h16) ; apa = pa@g (fp32)
    spmm2_k<<<NA / 32, 256, 0, stream>>>(csr_all, off_pa, cnt_pa,
                                         (const uint4*)pap16, (const uint4*)zp16,
                                         nullptr, (uint4*)h16,
                                         (float4*)out_apa, nullptr, NA);
    // pass 4: papap = ap@h2 (fp32)
    spmm_k<<<NP / 32, 256, 0, stream>>>(csr_all, off_ap, cnt_ap, (const uint4*)h16,
                                        (float4*)out_papap, nullptr, NP);
}

// Round 8
// 678.172 us; speedup vs baseline: 2.4960x; 1.1565x over previous
//
#include <hip/hip_runtime.h>
#include <hip/hip_fp16.h>

#define NP 200000
#define NA 100000
#define NE 1200000
#define NTOT (NA + NP)
#define NBP_GEMM 3125           // NP/64
#define NBA_GEMM 1563           // ceil(NA/64)

// partitioned CSR build geometry
#define CHUNK 4096              // edges per partition block (16/thread)
#define NCHUNK 586              // ceil(2*NE / CHUNK)
#define NBUCKA 98               // ceil(NA/1024)
#define NBUCKP 196              // ceil(NP/1024)
#define NBUCK (NBUCKA + NBUCKP) // 294
#define MATN (NBUCK * NCHUNK)   // 172284

typedef _Float16 half8 __attribute__((ext_vector_type(8)));
typedef float f32x4 __attribute__((ext_vector_type(4)));

// ---------------- scans (exclusive) ----------------

__global__ __launch_bounds__(256) void scan1_k(const int* __restrict__ in, int* __restrict__ out,
                                               int* __restrict__ bsums, int n) {
    __shared__ int lds[256];
    int t = threadIdx.x;
    int base = blockIdx.x * 1024 + t * 4;
    int v0 = (base + 0 < n) ? in[base + 0] : 0;
    int v1 = (base + 1 < n) ? in[base + 1] : 0;
    int v2 = (base + 2 < n) ? in[base + 2] : 0;
    int v3 = (base + 3 < n) ? in[base + 3] : 0;
    lds[t] = v0 + v1 + v2 + v3;
    __syncthreads();
    for (int off = 1; off < 256; off <<= 1) {
        int x = (t >= off) ? lds[t - off] : 0;
        __syncthreads();
        lds[t] += x;
        __syncthreads();
    }
    if (t == 255) bsums[blockIdx.x] = lds[255];
    int run = (t == 0) ? 0 : lds[t - 1];
    if (base + 0 < n) out[base + 0] = run; run += v0;
    if (base + 1 < n) out[base + 1] = run; run += v1;
    if (base + 2 < n) out[base + 2] = run; run += v2;
    if (base + 3 < n) out[base + 3] = run;
}

__global__ __launch_bounds__(1024) void scan2_k(int* bsums, int nb) {  // nb <= 1024, single block
    __shared__ int lds[1024];
    int t = threadIdx.x;
    int v = (t < nb) ? bsums[t] : 0;
    lds[t] = v;
    __syncthreads();
    for (int off = 1; off < 1024; off <<= 1) {
        int x = (t >= off) ? lds[t - off] : 0;
        __syncthreads();
        lds[t] += x;
        __syncthreads();
    }
    if (t < nb) bsums[t] = lds[t] - v;  // exclusive
}

__global__ __launch_bounds__(256) void scan3_k(int* __restrict__ out, const int* __restrict__ bsums, int n) {
    int add = bsums[blockIdx.x];
    int base = blockIdx.x * 1024 + threadIdx.x * 4;
#pragma unroll
    for (int j = 0; j < 4; j++)
        if (base + j < n) out[base + j] += add;
}

// ---------------- partitioned CSR build ----------------
// Buckets: 1024 combined rows each. [authors: buckets 0..97 | papers: 98..293].
// No global atomics anywhere; staged + final writes are cache-line-friendly.

__device__ __forceinline__ int bucket_gbase(int b) {
    return (b < NBUCKA) ? (b << 10) : NA + ((b - NBUCKA) << 10);
}
__device__ __forceinline__ int bucket_nrows(int b) {
    return (b < NBUCKA) ? min(1024, NA - (b << 10)) : min(1024, NP - ((b - NBUCKA) << 10));
}

// pass A1: per-(bucket, chunk) edge counts
__global__ __launch_bounds__(256) void part_cnt_k(const int* __restrict__ pa_row, const int* __restrict__ ap_row,
                                                  int* __restrict__ mat) {
    __shared__ int lh[NBUCK];
    int t = threadIdx.x, c = blockIdx.x;
    for (int b = t; b < NBUCK; b += 256) lh[b] = 0;
    __syncthreads();
    int base = c * CHUNK;
#pragma unroll
    for (int k = 0; k < CHUNK / 256; k++) {
        int i = base + k * 256 + t;
        if (i < 2 * NE) {
            int b = (i < NE) ? (pa_row[i] >> 10) : (NBUCKA + (ap_row[i - NE] >> 10));
            atomicAdd(&lh[b], 1);
        }
    }
    __syncthreads();
    for (int b = t; b < NBUCK; b += 256) mat[b * NCHUNK + c] = lh[b];
}

// pass A2: stage edges to bucket-contiguous regions (positions from scanned mat)
// record: x = (rowlocal<<20) | col  (col < 2^20, rowlocal < 1024), y = val bits
__global__ __launch_bounds__(256) void part_scat_k(const int* __restrict__ pa_row, const int* __restrict__ pa_col,
                                                   const float* __restrict__ pa_val,
                                                   const int* __restrict__ ap_row, const int* __restrict__ ap_col,
                                                   const float* __restrict__ ap_val,
                                                   const int* __restrict__ matoff, int2* __restrict__ staged) {
    __shared__ int lc[NBUCK];
    int t = threadIdx.x, c = blockIdx.x;
    for (int b = t; b < NBUCK; b += 256) lc[b] = 0;
    __syncthreads();
    int base = c * CHUNK;
#pragma unroll
    for (int k = 0; k < CHUNK / 256; k++) {
        int i = base + k * 256 + t;
        if (i < 2 * NE) {
            int b, rl, col; float v;
            if (i < NE) {
                int r = pa_row[i];
                b = r >> 10; rl = r & 1023; col = pa_col[i]; v = pa_val[i];
            } else {
                int r = ap_row[i - NE];
                b = NBUCKA + (r >> 10); rl = r & 1023; col = ap_col[i - NE]; v = ap_val[i - NE];
            }
            int rk = atomicAdd(&lc[b], 1);  // LDS rank within (block,bucket)
            staged[matoff[b * NCHUNK + c] + rk] = make_int2((rl << 20) | col, __float_as_int(v));
        }
    }
}

// pass B1: per-row counts from staged records (one block per bucket, LDS histogram)
__global__ __launch_bounds__(256) void bcnt_k(const int2* __restrict__ staged, const int* __restrict__ matoff,
                                              int* __restrict__ cnt_all) {
    __shared__ int lcnt[1024];
    int t = threadIdx.x, b = blockIdx.x;
    for (int r = t; r < 1024; r += 256) lcnt[r] = 0;
    __syncthreads();
    int s = matoff[b * NCHUNK];
    int e = (b + 1 < NBUCK) ? matoff[(b + 1) * NCHUNK] : 2 * NE;
    for (int i = s + t; i < e; i += 256) atomicAdd(&lcnt[staged[i].x >> 20], 1);
    __syncthreads();
    int gb = bucket_gbase(b), nr = bucket_nrows(b);
    for (int r = t; r < nr; r += 256) cnt_all[gb + r] = lcnt[r];
}

// pass B2: place into final CSR (LDS cursors; writes land in bucket's ~96KB L2 window)
__global__ __launch_bounds__(256) void place_k(const int2* __restrict__ staged, const int* __restrict__ matoff,
                                               const int* __restrict__ off_all, int2* __restrict__ csr_all) {
    __shared__ int lcur[1024];
    int t = threadIdx.x, b = blockIdx.x;
    for (int r = t; r < 1024; r += 256) lcur[r] = 0;
    __syncthreads();
    int s = matoff[b * NCHUNK];
    int e = (b + 1 < NBUCK) ? matoff[(b + 1) * NCHUNK] : 2 * NE;
    int gb = bucket_gbase(b);
    for (int i = s + t; i < e; i += 256) {
        int2 rec = staged[i];
        int rl = rec.x >> 20;
        int pos = off_all[gb + rl] + atomicAdd(&lcur[rl], 1);
        csr_all[pos] = make_int2(rec.x & 0xFFFFF, rec.y);
    }
}

// ---------------- SpMM gather, fp16 z-table (unchanged) ----------------

__device__ __forceinline__ void fma_h8(float acc[8], float v, uint4 r) {
    __half2 h0 = *(__half2*)&r.x;
    __half2 h1 = *(__half2*)&r.y;
    __half2 h2 = *(__half2*)&r.z;
    __half2 h3 = *(__half2*)&r.w;
    float2 f0 = __half22float2(h0);
    float2 f1 = __half22float2(h1);
    float2 f2 = __half22float2(h2);
    float2 f3 = __half22float2(h3);
    acc[0] = fmaf(v, f0.x, acc[0]);
    acc[1] = fmaf(v, f0.y, acc[1]);
    acc[2] = fmaf(v, f1.x, acc[2]);
    acc[3] = fmaf(v, f1.y, acc[3]);
    acc[4] = fmaf(v, f2.x, acc[4]);
    acc[5] = fmaf(v, f2.y, acc[5]);
    acc[6] = fmaf(v, f3.x, acc[6]);
    acc[7] = fmaf(v, f3.y, acc[7]);
}

__device__ __forceinline__ void store_h8(uint4* out16, int g, int l, const float acc[8]) {
    __half2 p0 = __floats2half2_rn(acc[0], acc[1]);
    __half2 p1 = __floats2half2_rn(acc[2], acc[3]);
    __half2 p2 = __floats2half2_rn(acc[4], acc[5]);
    __half2 p3 = __floats2half2_rn(acc[6], acc[7]);
    uint4 o;
    o.x = *(unsigned*)&p0;
    o.y = *(unsigned*)&p1;
    o.z = *(unsigned*)&p2;
    o.w = *(unsigned*)&p3;
    out16[(size_t)g * 8 + l] = o;
}

__device__ __forceinline__ void store_f8(float4* out32, int g, int l, const float acc[8]) {
    out32[(size_t)g * 16 + l * 2 + 0] = make_float4(acc[0], acc[1], acc[2], acc[3]);
    out32[(size_t)g * 16 + l * 2 + 1] = make_float4(acc[4], acc[5], acc[6], acc[7]);
}

__global__ __launch_bounds__(256) void spmm_k(const int2* __restrict__ csr, const int* __restrict__ off,
                                              const int* __restrict__ cnt, const uint4* __restrict__ z,
                                              float4* __restrict__ out32, uint4* __restrict__ out16,
                                              int nrows) {
    int g = blockIdx.x * 32 + (threadIdx.x >> 3);
    int l = threadIdx.x & 7;
    if (g >= nrows) return;
    int start = off[g], deg = cnt[g];
    float acc[8];
#pragma unroll
    for (int i = 0; i < 8; i++) acc[i] = 0.f;

    if (deg > 0) {
        int2 e[8];
#pragma unroll
        for (int k = 0; k < 8; k++) e[k] = csr[start + min(k, deg - 1)];
        for (int j = 0; j < deg; j += 8) {
            uint4 r[8];
#pragma unroll
            for (int k = 0; k < 8; k++) r[k] = z[e[k].x * 8 + l];
            float v[8];
#pragma unroll
            for (int k = 0; k < 8; k++) v[k] = (j + k < deg) ? __int_as_float(e[k].y) : 0.f;
            int2 en[8];
            bool more = (j + 8) < deg;
            if (more) {
#pragma unroll
                for (int k = 0; k < 8; k++) en[k] = csr[start + min(j + 8 + k, deg - 1)];
            }
#pragma unroll
            for (int k = 0; k < 8; k++) fma_h8(acc, v[k], r[k]);
            if (more) {
#pragma unroll
                for (int k = 0; k < 8; k++) e[k] = en[k];
            }
        }
    }
    if (out32) store_f8(out32, g, l, acc);
    if (out16) store_h8(out16, g, l, acc);
}

__global__ __launch_bounds__(256) void spmm2_k(const int2* __restrict__ csr, const int* __restrict__ off,
                                               const int* __restrict__ cnt,
                                               const uint4* __restrict__ zA, const uint4* __restrict__ zB,
                                               float4* __restrict__ outA32, uint4* __restrict__ outA16,
                                               float4* __restrict__ outB32, uint4* __restrict__ outB16,
                                               int nrows) {
    int g = blockIdx.x * 32 + (threadIdx.x >> 3);
    int l = threadIdx.x & 7;
    if (g >= nrows) return;
    int start = off[g], deg = cnt[g];
    float accA[8], accB[8];
#pragma unroll
    for (int i = 0; i < 8; i++) { accA[i] = 0.f; accB[i] = 0.f; }

    if (deg > 0) {
        int2 e[8];
#pragma unroll
        for (int k = 0; k < 8; k++) e[k] = csr[start + min(k, deg - 1)];
        for (int j = 0; j < deg; j += 8) {
            uint4 rA[8], rB[8];
#pragma unroll
            for (int k = 0; k < 8; k++) {
                int idx = e[k].x * 8 + l;
                rA[k] = zA[idx];
                rB[k] = zB[idx];
            }
            float v[8];
#pragma unroll
            for (int k = 0; k < 8; k++) v[k] = (j + k < deg) ? __int_as_float(e[k].y) : 0.f;
            int2 en[8];
            bool more = (j + 8) < deg;
            if (more) {
#pragma unroll
                for (int k = 0; k < 8; k++) en[k] = csr[start + min(j + 8 + k, deg - 1)];
            }
#pragma unroll
            for (int k = 0; k < 8; k++) {
                fma_h8(accA, v[k], rA[k]);
                fma_h8(accB, v[k], rB[k]);
            }
            if (more) {
#pragma unroll
                for (int k = 0; k < 8; k++) e[k] = en[k];
            }
        }
    }
    if (outA32) store_f8(outA32, g, l, accA);
    if (outA16) store_h8(outA16, g, l, accA);
    if (outB32) store_f8(outB32, g, l, accB);
    if (outB16) store_h8(outB16, g, l, accB);
}

// ---------------- dense projection via fp16 MFMA (unchanged) ----------------

__global__ __launch_bounds__(256) void wconv_k(const float* __restrict__ Wp, const float* __restrict__ Wa,
                                               __half* __restrict__ wtP, __half* __restrict__ wtA) {
    int i = blockIdx.x * 256 + threadIdx.x;
    int stride = gridDim.x * 256;
    for (int idx = i; idx < 64 * 256; idx += stride) {
        int c = idx >> 8, k = idx & 255;
        wtP[idx] = (__half)Wp[k * 64 + c];
    }
    for (int idx = i; idx < 64 * 128; idx += stride) {
        int c = idx >> 7, k = idx & 127;
        wtA[idx] = (__half)Wa[k * 64 + c];
    }
}

__global__ __launch_bounds__(256) void gemm_mfma_k(const float* __restrict__ xP, const float* __restrict__ xA,
                                                   const __half* __restrict__ wtP, const __half* __restrict__ wtA,
                                                   __half* __restrict__ zP, __half* __restrict__ zA) {
    int b = blockIdx.x;
    const float* x;
    const __half* wt;
    __half* z;
    int K, nrows, r0;
    if (b < NBP_GEMM) { x = xP; wt = wtP; z = zP; K = 256; nrows = NP; r0 = b * 64; }
    else              { x = xA; wt = wtA; z = zA; K = 128; nrows = NA; r0 = (b - NBP_GEMM) * 64; }

    int w = threadIdx.x >> 6;
    int l = threadIdx.x & 63;
    int arow = r0 + w * 16 + (l & 15);
    int kq = (l >> 4) * 8;

    f32x4 acc0 = {0.f, 0.f, 0.f, 0.f};
    f32x4 acc1 = {0.f, 0.f, 0.f, 0.f};
    f32x4 acc2 = {0.f, 0.f, 0.f, 0.f};
    f32x4 acc3 = {0.f, 0.f, 0.f, 0.f};

    for (int k0 = 0; k0 < K; k0 += 32) {
        half8 a;
        if (arow < nrows) {
            const float* xp = x + (size_t)arow * K + k0 + kq;
            float4 f0 = *(const float4*)xp;
            float4 f1 = *(const float4*)(xp + 4);
            a[0] = (_Float16)f0.x; a[1] = (_Float16)f0.y;
            a[2] = (_Float16)f0.z; a[3] = (_Float16)f0.w;
            a[4] = (_Float16)f1.x; a[5] = (_Float16)f1.y;
            a[6] = (_Float16)f1.z; a[7] = (_Float16)f1.w;
        } else {
#pragma unroll
            for (int j = 0; j < 8; j++) a[j] = (_Float16)0.f;
        }
        const __half* wbase = wt + (size_t)(l & 15) * K + k0 + kq;
        half8 b0 = *(const half8*)(wbase);
        half8 b1 = *(const half8*)(wbase + (size_t)16 * K);
        half8 b2 = *(const half8*)(wbase + (size_t)32 * K);
        half8 b3 = *(const half8*)(wbase + (size_t)48 * K);
        acc0 = __builtin_amdgcn_mfma_f32_16x16x32_f16(a, b0, acc0, 0, 0, 0);
        acc1 = __builtin_amdgcn_mfma_f32_16x16x32_f16(a, b1, acc1, 0, 0, 0);
        acc2 = __builtin_amdgcn_mfma_f32_16x16x32_f16(a, b2, acc2, 0, 0, 0);
        acc3 = __builtin_amdgcn_mfma_f32_16x16x32_f16(a, b3, acc3, 0, 0, 0);
    }

    int orow0 = r0 + w * 16 + (l >> 4) * 4;
    int col = l & 15;
#pragma unroll
    for (int i = 0; i < 4; i++) {
        int r = orow0 + i;
        if (r < nrows) {
            __half* zr = z + (size_t)r * 64;
            zr[col +  0] = (__half)acc0[i];
            zr[col + 16] = (__half)acc1[i];
            zr[col + 32] = (__half)acc2[i];
            zr[col + 48] = (__half)acc3[i];
        }
    }
}

// ---------------- launch ----------------

extern "C" void kernel_launch(void* const* d_in, const int* in_sizes, int n_in,
                              void* d_out, int out_size, void* d_ws, size_t ws_size,
                              hipStream_t stream) {
    const float* x_paper  = (const float*)d_in[0];
    const float* x_author = (const float*)d_in[1];
    const float* W_paper  = (const float*)d_in[2];
    const float* W_author = (const float*)d_in[3];
    const int*   pa_row   = (const int*)d_in[4];
    const int*   pa_col   = (const int*)d_in[5];
    const float* pa_val   = (const float*)d_in[6];
    const int*   ap_row   = (const int*)d_in[7];
    const int*   ap_col   = (const int*)d_in[8];
    const float* ap_val   = (const float*)d_in[9];

    char* ws = (char*)d_ws;
    size_t o = 0;
    auto alloc = [&](size_t bytes) -> char* {
        char* p = ws + o;
        o += (bytes + 255) & ~(size_t)255;
        return p;
    };
    __half* zp16  = (__half*)alloc((size_t)NP * 64 * 2);  // zp, later reused as g
    __half* za16  = (__half*)alloc((size_t)NA * 64 * 2);
    __half* h16   = (__half*)alloc((size_t)NA * 64 * 2);  // h, later h2
    __half* pap16 = (__half*)alloc((size_t)NP * 64 * 2);
    int2*  csr_all = (int2*)alloc((size_t)2 * NE * 8);
    int2*  staged  = (int2*)alloc((size_t)2 * NE * 8);
    int* mat     = (int*)alloc((size_t)MATN * 4);
    int* matoff  = (int*)alloc((size_t)MATN * 4);
    int* cnt_all = (int*)alloc(NTOT * 4);
    int* off_all = (int*)alloc(NTOT * 4);
    int* bsums   = (int*)alloc(1024 * 4);
    __half* wtP  = (__half*)alloc(64 * 256 * 2);
    __half* wtA  = (__half*)alloc(64 * 128 * 2);

    float* out_pap   = (float*)d_out;
    float* out_papap = out_pap + (size_t)NP * 64;
    float* out_apa   = out_papap + (size_t)NP * 64;

    const int nb_mat = (MATN + 1023) / 1024;  // 169
    const int nb_tot = (NTOT + 1023) / 1024;  // 293

    // ---- partitioned CSR build (no global atomics, no memsets) ----
    part_cnt_k<<<NCHUNK, 256, 0, stream>>>(pa_row, ap_row, mat);
    scan1_k<<<nb_mat, 256, 0, stream>>>(mat, matoff, bsums, MATN);
    scan2_k<<<1, 1024, 0, stream>>>(bsums, nb_mat);
    scan3_k<<<nb_mat, 256, 0, stream>>>(matoff, bsums, MATN);
    part_scat_k<<<NCHUNK, 256, 0, stream>>>(pa_row, pa_col, pa_val, ap_row, ap_col, ap_val,
                                            matoff, staged);
    bcnt_k<<<NBUCK, 256, 0, stream>>>(staged, matoff, cnt_all);
    scan1_k<<<nb_tot, 256, 0, stream>>>(cnt_all, off_all, bsums, NTOT);
    scan2_k<<<1, 1024, 0, stream>>>(bsums, nb_tot);
    scan3_k<<<nb_tot, 256, 0, stream>>>(off_all, bsums, NTOT);
    place_k<<<NBUCK, 256, 0, stream>>>(staged, matoff, off_all, csr_all);

    // ---- projections (fp16 MFMA) ----
    wconv_k<<<64, 256, 0, stream>>>(W_paper, W_author, wtP, wtA);
    gemm_mfma_k<<<NBP_GEMM + NBA_GEMM, 256, 0, stream>>>(x_paper, x_author, wtP, wtA, zp16, za16);

    const int* off_pa = off_all;        // author rows
    const int* cnt_pa = cnt_all;
    const int* off_ap = off_all + NA;   // paper rows
    const int* cnt_ap = cnt_all + NA;

    // pass 1: h = pa@zp (fp16)
    spmm_k<<<NA / 32, 256, 0, stream>>>(csr_all, off_pa, cnt_pa, (const uint4*)zp16,
                                        nullptr, (uint4*)h16, NA);
    // pass 2 (fused over ap): pap = ap@h (fp32 + fp16) ; g = ap@za (fp16, reuse zp16)
    spmm2_k<<<NP / 32, 256, 0, stream>>>(csr_all, off_ap, cnt_ap,
                                         (const uint4*)h16, (const uint4*)za16,
                                         (float4*)out_pap, (uint4*)pap16,
                                         nullptr, (uint4*)zp16, NP);
    // pass 3 (fused over pa): h2 = pa@pap (fp16, reuse h16) ; apa = pa@g (fp32)
    spmm2_k<<<NA / 32, 256, 0, stream>>>(csr_all, off_pa, cnt_pa,
                                         (const uint4*)pap16, (const uint4*)zp16,
                                         nullptr, (uint4*)h16,
                                         (float4*)out_apa, nullptr, NA);
    // pass 4: papap = ap@h2 (fp32)
    spmm_k<<<NP / 32, 256, 0, stream>>>(csr_all, off_ap, cnt_ap, (const uint4*)h16,
                                        (float4*)out_papap, nullptr, NP);
}